// Round 4
// baseline (1773.814 us; speedup 1.0000x reference)
//
#include <hip/hip_runtime.h>

#define TT   2048
#define DD   1024
#define NLAY 4
#define VPAD 50304
#define RANKK 64
#define CH   128
#define NCH  16   // TT/CH

typedef float f32x4 __attribute__((ext_vector_type(4)));
typedef int   i32x4 __attribute__((ext_vector_type(4)));

__device__ __forceinline__ float siluf(float v) { return v / (1.0f + expf(-v)); }

__device__ __forceinline__ unsigned short f2bf(float f) {
    unsigned int u = __float_as_uint(f);
    u = (u + 0x7fffu + ((u >> 16) & 1u)) >> 16;
    return (unsigned short)u;
}

// ---------------- embed: x = wte[idx] + wpe ----------------
__global__ void k_embed(const int* __restrict__ idx, const float* __restrict__ wte,
                        const float* __restrict__ wpe, float* __restrict__ x) {
    int t = blockIdx.x;
    int i = threadIdx.x * 4;
    int tok = idx[t];
    float4 a = *(const float4*)(wte + (size_t)tok * DD + i);
    float4 b = *(const float4*)(wpe + (size_t)t * DD + i);
    float4 o;
    o.x = a.x + b.x; o.y = a.y + b.y; o.z = a.z + b.z; o.w = a.w + b.w;
    *(float4*)(x + (size_t)t * DD + i) = o;
}

// ---------------- rmsnorm (f32 -> f32) ----------------
__global__ void k_rms(const float* __restrict__ s, float* __restrict__ d) {
    int t = blockIdx.x, tid = threadIdx.x;
    float4 v = *(const float4*)(s + (size_t)t * DD + tid * 4);
    float ss = v.x * v.x + v.y * v.y + v.z * v.z + v.w * v.w;
#pragma unroll
    for (int o = 32; o; o >>= 1) ss += __shfl_xor(ss, o, 64);
    __shared__ float red[4];
    if ((tid & 63) == 0) red[tid >> 6] = ss;
    __syncthreads();
    float tot = red[0] + red[1] + red[2] + red[3];
    float sc = rsqrtf(tot * (1.0f / 1024.0f) + 1.1920929e-7f);
    float4 o;
    o.x = v.x * sc; o.y = v.y * sc; o.z = v.z * sc; o.w = v.w * sc;
    *(float4*)(d + (size_t)t * DD + tid * 4) = o;
}

// ---------------- rmsnorm (f32 -> bf16) ----------------
__global__ void k_rms16(const float* __restrict__ s, unsigned short* __restrict__ d) {
    int t = blockIdx.x, tid = threadIdx.x;
    float4 v = *(const float4*)(s + (size_t)t * DD + tid * 4);
    float ss = v.x * v.x + v.y * v.y + v.z * v.z + v.w * v.w;
#pragma unroll
    for (int o = 32; o; o >>= 1) ss += __shfl_xor(ss, o, 64);
    __shared__ float red[4];
    if ((tid & 63) == 0) red[tid >> 6] = ss;
    __syncthreads();
    float tot = red[0] + red[1] + red[2] + red[3];
    float sc = rsqrtf(tot * (1.0f / 1024.0f) + 1.1920929e-7f);
    ushort4 o;
    o.x = f2bf(v.x * sc); o.y = f2bf(v.y * sc); o.z = f2bf(v.z * sc); o.w = f2bf(v.w * sc);
    *(ushort4*)(d + (size_t)t * DD + tid * 4) = o;
}

// ---------------- fused bseq/bdep blockdiag + silu + gain ----------------
// drive = silu(blockdiag(e, wseq)); hdep = gain * silu(blockdiag(e, wdep))
__global__ void k_bd2(const float* __restrict__ e, const float* __restrict__ wseq_g,
                      const float* __restrict__ wdep_g, const float* __restrict__ logAd,
                      const float* __restrict__ logdtd, const int* __restrict__ kptr,
                      float* __restrict__ drive, float* __restrict__ hdep) {
    __shared__ float ws[64][65], wd[64][65], et[16][68];
    int t0 = blockIdx.x * 16, n = blockIdx.y, tid = threadIdx.x;
    const float* wsg = wseq_g + n * 4096;
    const float* wdg = wdep_g + n * 4096;
    for (int i = tid; i < 4096; i += 256) { ws[i >> 6][i & 63] = wsg[i]; wd[i >> 6][i & 63] = wdg[i]; }
    for (int i = tid; i < 1024; i += 256) {
        int r = i >> 6, c = i & 63;
        et[r][c] = e[(size_t)(t0 + r) * DD + n * 64 + c];
    }
    __syncthreads();
    int tl = tid & 15, o0 = (tid >> 4) * 4;
    float as[4] = {0, 0, 0, 0}, ad[4] = {0, 0, 0, 0};
    for (int i = 0; i < 64; i++) {
        float ev = et[tl][i];
#pragma unroll
        for (int j = 0; j < 4; j++) {
            as[j] = fmaf(ev, ws[o0 + j][i], as[j]);
            ad[j] = fmaf(ev, wd[o0 + j][i], ad[j]);
        }
    }
    int K = *kptr;
    float dv[4], hv[4];
#pragma unroll
    for (int j = 0; j < 4; j++) {
        int c = n * 64 + o0 + j;
        float g;
        if (c < 64) {
            g = (float)K;
        } else {
            float a = expf(-expf(logAd[c - 64] + logdtd[c - 64]));
            float om = 1.0f - a;
            float aK = 1.0f;
            for (int q = 0; q < K; q++) aK *= a;
            g = (fabsf(om) < 1e-6f) ? (float)K : (1.0f - aK) / fmaxf(om, 1e-8f);
        }
        dv[j] = siluf(as[j]);
        hv[j] = g * siluf(ad[j]);
    }
    float4 dq, hq;
    dq.x = dv[0]; dq.y = dv[1]; dq.z = dv[2]; dq.w = dv[3];
    hq.x = hv[0]; hq.y = hv[1]; hq.z = hv[2]; hq.w = hv[3];
    *(float4*)(drive + (size_t)(t0 + tl) * DD + n * 64 + o0) = dq;
    *(float4*)(hdep  + (size_t)(t0 + tl) * DD + n * 64 + o0) = hq;
}

// ---------------- scan pass 1: local chunk scans ----------------
__global__ void k_scan1(const float* __restrict__ drive, const float* __restrict__ la,
                        const float* __restrict__ ldt, float* __restrict__ hs,
                        float* __restrict__ carry) {
    __shared__ float tile[CH][64];
    int cid = blockIdx.x, d0 = blockIdx.y * 64, tid = threadIdx.x;
    int t0 = cid * CH;
    for (int i = tid; i < CH * 16; i += 64) {
        int r = i >> 4, q = (i & 15) * 4;
        *(float4*)&tile[r][q] = *(const float4*)(drive + (size_t)(t0 + r) * DD + d0 + q);
    }
    __syncthreads();
    int d = d0 + tid;
    float ac = fmaxf(expf(-expf(la[d] + ldt[d])), 1e-6f);
    float y = 0.0f;
    for (int t = 0; t < CH; t++) {
        y = fmaf(ac, y, tile[t][tid]);
        hs[(size_t)(t0 + t) * DD + d] = y;
    }
    carry[cid * DD + d] = y;
}

// ---------------- scan pass 2: cross-chunk carries ----------------
__global__ void k_scan2(const float* __restrict__ carry, const float* __restrict__ la,
                        const float* __restrict__ ldt, float* __restrict__ yprev,
                        float* __restrict__ l2a) {
    int d = blockIdx.x * 256 + threadIdx.x;
    float ac = fmaxf(expf(-expf(la[d] + ldt[d])), 1e-6f);
    float A = powf(ac, (float)CH);
    float y = 0.0f;
    for (int c = 0; c < NCH; c++) {
        yprev[c * DD + d] = y;
        y = fmaf(A, y, carry[c * DD + d]);
    }
    l2a[d] = log2f(ac);
}

// ---------------- scan pass 3: apply carry, h = hs + corr + hdep ----------------
__global__ void k_scan3(const float* __restrict__ hs, const float* __restrict__ hdep,
                        const float* __restrict__ yprev, const float* __restrict__ l2a,
                        float* __restrict__ h) {
    int t = blockIdx.x;
    int tl = t & (CH - 1), c = t >> 7;
    int d0 = threadIdx.x * 4;
    float4 a = *(const float4*)(hs + (size_t)t * DD + d0);
    float4 b = *(const float4*)(hdep + (size_t)t * DD + d0);
    float4 yp = *(const float4*)(yprev + c * DD + d0);
    float4 lg = *(const float4*)(l2a + d0);
    float tp = (float)(tl + 1);
    float4 o;
    o.x = a.x + exp2f(tp * lg.x) * yp.x + b.x;
    o.y = a.y + exp2f(tp * lg.y) * yp.y + b.y;
    o.z = a.z + exp2f(tp * lg.z) * yp.z + b.z;
    o.w = a.w + exp2f(tp * lg.w) * yp.w + b.w;
    *(float4*)(h + (size_t)t * DD + d0) = o;
}

// ---------------- wpost blockdiag over concat([hn, e, shifted]) + silu ----------------
__global__ void k_wpost(const float* __restrict__ hn, const float* __restrict__ e,
                        const float* __restrict__ wp_g, float* __restrict__ r) {
    __shared__ float wp[64][193];
    __shared__ float it[16][196];
    int t0 = blockIdx.x * 16, n = blockIdx.y, tid = threadIdx.x;
    const float* wg = wp_g + n * 64 * 192;
    for (int i = tid; i < 64 * 192; i += 256) wp[i / 192][i % 192] = wg[i];
    for (int i = tid; i < 16 * 192; i += 256) {
        int tl = i / 192, ii = i % 192;
        int gi = n * 192 + ii;
        int t = t0 + tl;
        float v;
        if (gi < 1024)       v = hn[(size_t)t * DD + gi];
        else if (gi < 2048)  v = e[(size_t)t * DD + gi - 1024];
        else                 v = (t > 0) ? e[(size_t)(t - 1) * DD + gi - 2048] : 0.0f;
        it[tl][ii] = v;
    }
    __syncthreads();
    int tl = tid & 15, o0 = (tid >> 4) * 4;
    float acc[4] = {0, 0, 0, 0};
    for (int i = 0; i < 192; i++) {
        float iv = it[tl][i];
#pragma unroll
        for (int j = 0; j < 4; j++) acc[j] = fmaf(iv, wp[o0 + j][i], acc[j]);
    }
    float4 o;
    o.x = siluf(acc[0]); o.y = siluf(acc[1]); o.z = siluf(acc[2]); o.w = siluf(acc[3]);
    *(float4*)(r + (size_t)(t0 + tl) * DD + n * 64 + o0) = o;
}

// ---------------- t1 = r @ lowB^T  (T x RANK) ----------------
__global__ void k_lowb(const float* __restrict__ r, const float* __restrict__ lowB,
                       float* __restrict__ t1) {
    __shared__ float rt[8][DD];
    int t0 = blockIdx.x * 8, tid = threadIdx.x;
    for (int i = tid; i < 8 * 256; i += 256) {
        int row = i >> 8, q = (i & 255) * 4;
        *(float4*)&rt[row][q] = *(const float4*)(r + (size_t)(t0 + row) * DD + q);
    }
    __syncthreads();
    int tl = tid >> 5, rk = (tid & 31) * 2;
    float a0 = 0.0f, a1 = 0.0f;
    for (int k = 0; k < DD; k += 4) {
        float4 rv = *(const float4*)&rt[tl][k];
        float4 b0 = *(const float4*)(lowB + (size_t)rk * DD + k);
        float4 b1 = *(const float4*)(lowB + (size_t)(rk + 1) * DD + k);
        a0 += rv.x * b0.x + rv.y * b0.y + rv.z * b0.z + rv.w * b0.w;
        a1 += rv.x * b1.x + rv.y * b1.y + rv.z * b1.z + rv.w * b1.w;
    }
    t1[(size_t)(t0 + tl) * RANKK + rk] = a0;
    t1[(size_t)(t0 + tl) * RANKK + rk + 1] = a1;
}

// ---------------- x += blockdiag(r, wlocal) + t1 @ lowA^T ----------------
__global__ void k_upd(const float* __restrict__ r, const float* __restrict__ t1,
                      const float* __restrict__ wl_g, const float* __restrict__ lowA_l,
                      float* __restrict__ x) {
    __shared__ float wl[64][65], la[64][65], rt[16][68], tb[16][68];
    int t0 = blockIdx.x * 16, n = blockIdx.y, tid = threadIdx.x;
    const float* wg = wl_g + n * 4096;
    const float* lg = lowA_l + n * 4096;   // rows n*64.., each RANKK=64 wide
    for (int i = tid; i < 4096; i += 256) { wl[i >> 6][i & 63] = wg[i]; la[i >> 6][i & 63] = lg[i]; }
    for (int i = tid; i < 1024; i += 256) {
        int row = i >> 6, c = i & 63;
        rt[row][c] = r[(size_t)(t0 + row) * DD + n * 64 + c];
        tb[row][c] = t1[(size_t)(t0 + row) * RANKK + c];
    }
    __syncthreads();
    int tl = tid & 15, o0 = (tid >> 4) * 4;
    float acc[4] = {0, 0, 0, 0};
    for (int i = 0; i < 64; i++) {
        float rv = rt[tl][i], tv = tb[tl][i];
#pragma unroll
        for (int j = 0; j < 4; j++)
            acc[j] = fmaf(rv, wl[o0 + j][i], fmaf(tv, la[o0 + j][i], acc[j]));
    }
    float* xp = x + (size_t)(t0 + tl) * DD + n * 64 + o0;
    float4 xv = *(float4*)xp;
    xv.x += acc[0]; xv.y += acc[1]; xv.z += acc[2]; xv.w += acc[3];
    *(float4*)xp = xv;
}

// ---------------- cast lm_head weights f32 -> bf16 ----------------
__global__ void k_castw(const float* __restrict__ w, unsigned short* __restrict__ w16) {
    size_t stride = (size_t)gridDim.x * blockDim.x;
    size_t n4 = (size_t)VPAD * DD / 4;
    for (size_t i = (size_t)blockIdx.x * blockDim.x + threadIdx.x; i < n4; i += stride) {
        float4 v = *(const float4*)(w + i * 4);
        ushort4 o;
        o.x = f2bf(v.x); o.y = f2bf(v.y); o.z = f2bf(v.z); o.w = f2bf(v.w);
        *(ushort4*)(w16 + i * 4) = o;
    }
}

// ---------------- lm_head GEMM: out[m,n] = sum_k A[m,k]*W[n,k], bf16 MFMA ----------------
__device__ __forceinline__ void mfma16(f32x4& d, i32x4 a, i32x4 b) {
    asm volatile("v_mfma_f32_16x16x32_bf16 %0, %1, %2, %0" : "+v"(d) : "v"(a), "v"(b));
}

#define LDK 40  // padded LDS row (ushorts) to break bank-conflict stride

__global__ __launch_bounds__(256) void k_gemm(const unsigned short* __restrict__ A,
                                              const unsigned short* __restrict__ B,
                                              float* __restrict__ C) {
    __shared__ unsigned short As[128 * LDK], Bs[128 * LDK];
    int tid = threadIdx.x;
    int lane = tid & 63, wv = tid >> 6, wr = wv >> 1, wc = wv & 1;
    int bn = blockIdx.x, bm = blockIdx.y;
    const unsigned short* Ab = A + (size_t)bm * 128 * 1024;
    const unsigned short* Bb = B + (size_t)bn * 128 * 1024;
    f32x4 acc[4][4] = {};
    int c0r = tid >> 2, cq = (tid & 3) * 8;
    int c1r = c0r + 64;
    int lrow = lane & 15, lkg = (lane >> 4) * 8;
    for (int kt = 0; kt < 1024; kt += 32) {
        i32x4 a0 = *(const i32x4*)(Ab + (size_t)c0r * 1024 + kt + cq);
        i32x4 a1 = *(const i32x4*)(Ab + (size_t)c1r * 1024 + kt + cq);
        i32x4 b0 = *(const i32x4*)(Bb + (size_t)c0r * 1024 + kt + cq);
        i32x4 b1 = *(const i32x4*)(Bb + (size_t)c1r * 1024 + kt + cq);
        __syncthreads();
        *(i32x4*)(As + c0r * LDK + cq) = a0;
        *(i32x4*)(As + c1r * LDK + cq) = a1;
        *(i32x4*)(Bs + c0r * LDK + cq) = b0;
        *(i32x4*)(Bs + c1r * LDK + cq) = b1;
        __syncthreads();
        i32x4 af[4], bf[4];
#pragma unroll
        for (int i = 0; i < 4; i++) af[i] = *(const i32x4*)(As + (wr * 64 + i * 16 + lrow) * LDK + lkg);
#pragma unroll
        for (int i = 0; i < 4; i++) bf[i] = *(const i32x4*)(Bs + (wc * 64 + i * 16 + lrow) * LDK + lkg);
#pragma unroll
        for (int mi = 0; mi < 4; mi++)
#pragma unroll
            for (int ni = 0; ni < 4; ni++)
                mfma16(acc[mi][ni], af[mi], bf[ni]);
    }
    int lq = lane >> 4;
#pragma unroll
    for (int mi = 0; mi < 4; mi++) {
#pragma unroll
        for (int ni = 0; ni < 4; ni++) {
            int row = bm * 128 + wr * 64 + mi * 16 + lq * 4;
            int col = bn * 128 + wc * 64 + ni * 16 + lrow;
#pragma unroll
            for (int q = 0; q < 4; q++)
                C[(size_t)(row + q) * VPAD + col] = acc[mi][ni][q];
        }
    }
}

extern "C" void kernel_launch(void* const* d_in, const int* in_sizes, int n_in,
                              void* d_out, int out_size, void* d_ws, size_t ws_size,
                              hipStream_t stream) {
    const int*   idx  = (const int*)d_in[0];
    const int*   akp  = (const int*)d_in[1];
    const float* wte  = (const float*)d_in[2];
    const float* wpe  = (const float*)d_in[3];
    const float* bseq = (const float*)d_in[4];
    const float* lAs  = (const float*)d_in[5];
    const float* ldts = (const float*)d_in[6];
    const float* bdep = (const float*)d_in[7];
    const float* lAd  = (const float*)d_in[8];
    const float* ldtd = (const float*)d_in[9];
    const float* wpg  = (const float*)d_in[10];
    const float* wlg  = (const float*)d_in[11];
    const float* lowA = (const float*)d_in[12];
    const float* lowB = (const float*)d_in[13];
    const float* lmw  = (const float*)d_in[14];
    float* out = (float*)d_out;

    char* p = (char*)d_ws;
    unsigned short* W16 = (unsigned short*)p; p += (size_t)VPAD * DD * 2;
    unsigned short* A16 = (unsigned short*)p; p += (size_t)TT * DD * 2;
    float* x     = (float*)p; p += (size_t)TT * DD * 4;
    float* e     = (float*)p; p += (size_t)TT * DD * 4;
    float* drive = (float*)p; p += (size_t)TT * DD * 4;
    float* hdep  = (float*)p; p += (size_t)TT * DD * 4;
    float* hs    = (float*)p; p += (size_t)TT * DD * 4;
    float* h     = (float*)p; p += (size_t)TT * DD * 4;
    float* hn    = (float*)p; p += (size_t)TT * DD * 4;
    float* r     = (float*)p; p += (size_t)TT * DD * 4;
    float* t1    = (float*)p; p += (size_t)TT * RANKK * 4;
    float* carry = (float*)p; p += (size_t)NCH * DD * 4;
    float* yprev = (float*)p; p += (size_t)NCH * DD * 4;
    float* l2a   = (float*)p; p += (size_t)DD * 4;

    // weight cast can start immediately (independent of layer pipeline)
    k_castw<<<2048, 256, 0, stream>>>(lmw, W16);

    k_embed<<<TT, 256, 0, stream>>>(idx, wte, wpe, x);

    for (int l = 0; l < NLAY; l++) {
        const float* bseq_l = bseq + (size_t)l * 65536;
        const float* bdep_l = bdep + (size_t)l * 65536;
        const float* lAs_l  = lAs  + (size_t)l * DD;
        const float* ldts_l = ldts + (size_t)l * DD;
        const float* lAd_l  = lAd  + (size_t)l * 960;
        const float* ldtd_l = ldtd + (size_t)l * 960;
        const float* wpg_l  = wpg  + (size_t)l * 196608;
        const float* wlg_l  = wlg  + (size_t)l * 65536;
        const float* lowA_l = lowA + (size_t)l * 65536;
        const float* lowB_l = lowB + (size_t)l * 65536;

        k_rms<<<TT, 256, 0, stream>>>(x, e);
        k_bd2<<<dim3(TT / 16, 16), 256, 0, stream>>>(e, bseq_l, bdep_l, lAd_l, ldtd_l, akp, drive, hdep);
        k_scan1<<<dim3(NCH, DD / 64), 64, 0, stream>>>(drive, lAs_l, ldts_l, hs, carry);
        k_scan2<<<4, 256, 0, stream>>>(carry, lAs_l, ldts_l, yprev, l2a);
        k_scan3<<<TT, 256, 0, stream>>>(hs, hdep, yprev, l2a, h);
        k_rms<<<TT, 256, 0, stream>>>(h, hn);
        k_wpost<<<dim3(TT / 16, 16), 256, 0, stream>>>(hn, e, wpg_l, r);
        k_lowb<<<TT / 8, 256, 0, stream>>>(r, lowB_l, t1);
        k_upd<<<dim3(TT / 16, 16), 256, 0, stream>>>(r, t1, wlg_l, lowA_l, x);
    }

    k_rms16<<<TT, 256, 0, stream>>>(x, A16);
    k_gemm<<<dim3(VPAD / 128, TT / 128), 256, 0, stream>>>(A16, W16, out);
}